// Round 2
// baseline (323.776 us; speedup 1.0000x reference)
//
#include <hip/hip_runtime.h>

// out = a*residual + b*sublayer where (a,b) are column sums of the 50-iter
// Sinkhorn-Knopp projection of a 2x2 matrix (both converge to 1 +/- ulps).
//
// Memory-bound streaming kernel. Structure:
//   1. every thread issues ALL its global loads first (16 x dwordx4 in
//      flight, 256 B/thread) -- memory streams while...
//   2. ...thread 0 of the block runs the 2x2 Sinkhorn (recip-mul form,
//      4 precise divides/iter), broadcast via LDS + one barrier,
//   3. straight-line FMA + nontemporal dwordx4 stores (output is never
//      re-read; keep it from evicting the L3-resident input halves).

typedef float f4 __attribute__((ext_vector_type(4)));

#define SK_ITERS 50
constexpr int BLOCK = 256;
constexpr int VPT   = 8;             // float4 chunks per thread
constexpr int CPB   = BLOCK * VPT;   // 2048 float4 per block

__device__ __forceinline__ void sinkhorn_ab(const float* __restrict__ W,
                                            float& a, float& b) {
    // W row-major 2x2: [W00, W01, W10, W11]
    float w00 = fabsf(W[0]) + 1e-8f;
    float w01 = fabsf(W[1]) + 1e-8f;
    float w10 = fabsf(W[2]) + 1e-8f;
    float w11 = fabsf(W[3]) + 1e-8f;
    #pragma unroll 1
    for (int i = 0; i < SK_ITERS; ++i) {
        float t0 = 1.0f / (w00 + w01);   // row-normalize
        float t1 = 1.0f / (w10 + w11);
        w00 *= t0; w01 *= t0; w10 *= t1; w11 *= t1;
        float u0 = 1.0f / (w00 + w10);   // col-normalize
        float u1 = 1.0f / (w01 + w11);
        w00 *= u0; w10 *= u0; w01 *= u1; w11 *= u1;
    }
    a = w00 + w10;   // column-0 sum
    b = w01 + w11;   // column-1 sum
}

__global__ __launch_bounds__(BLOCK) void sinkhorn_mix_kernel(
    const f4* __restrict__ r4, const f4* __restrict__ s4, f4* __restrict__ o4,
    const float* __restrict__ W_raw,
    const float* __restrict__ rs, const float* __restrict__ ss,
    float* __restrict__ os,
    long long n4, long long n)
{
    __shared__ float s_ab[2];

    const long long blockStart = (long long)blockIdx.x * CPB;
    const long long tbase      = blockStart + threadIdx.x;
    const bool full = (blockStart + CPB) <= n4;

    f4 rv[VPT], sv[VPT];

    // ---- phase 1: fire all loads (before the sinkhorn/barrier bubble) ----
    if (full) {
        #pragma unroll
        for (int k = 0; k < VPT; ++k) rv[k] = r4[tbase + (long long)k * BLOCK];
        #pragma unroll
        for (int k = 0; k < VPT; ++k) sv[k] = s4[tbase + (long long)k * BLOCK];
    }

    // ---- phase 2: 2x2 Sinkhorn on one lane, broadcast through LDS ----
    if (threadIdx.x == 0) {
        float a, b;
        sinkhorn_ab(W_raw, a, b);
        s_ab[0] = a; s_ab[1] = b;
    }
    __syncthreads();
    const float a = s_ab[0], b = s_ab[1];

    // ---- phase 3: FMA + streaming stores ----
    if (full) {
        #pragma unroll
        for (int k = 0; k < VPT; ++k) {
            f4 ov;
            ov.x = a * rv[k].x + b * sv[k].x;
            ov.y = a * rv[k].y + b * sv[k].y;
            ov.z = a * rv[k].z + b * sv[k].z;
            ov.w = a * rv[k].w + b * sv[k].w;
            __builtin_nontemporal_store(ov, &o4[tbase + (long long)k * BLOCK]);
        }
    } else {
        // guarded tail block: per-chunk bounds check + scalar remainder
        #pragma unroll 1
        for (int k = 0; k < VPT; ++k) {
            long long i = tbase + (long long)k * BLOCK;
            if (i < n4) {
                f4 rvk = r4[i], svk = s4[i];
                f4 ov;
                ov.x = a * rvk.x + b * svk.x;
                ov.y = a * rvk.y + b * svk.y;
                ov.z = a * rvk.z + b * svk.z;
                ov.w = a * rvk.w + b * svk.w;
                o4[i] = ov;
            }
        }
        if (blockIdx.x == (int)gridDim.x - 1) {
            for (long long e = 4 * n4 + threadIdx.x; e < n; e += BLOCK) {
                os[e] = a * rs[e] + b * ss[e];
            }
        }
    }
}

extern "C" void kernel_launch(void* const* d_in, const int* in_sizes, int n_in,
                              void* d_out, int out_size, void* d_ws, size_t ws_size,
                              hipStream_t stream) {
    const float* residual = (const float*)d_in[0];
    const float* sublayer = (const float*)d_in[1];
    const float* W_raw    = (const float*)d_in[2];
    float* out            = (float*)d_out;

    const long long n  = (long long)out_size;   // 2*4096*4096 = 33,554,432
    const long long n4 = n >> 2;                // 8,388,608 float4 chunks

    long long grid = (n4 + CPB - 1) / CPB;      // 4096 blocks for this size
    if (grid < 1) grid = 1;

    sinkhorn_mix_kernel<<<(int)grid, BLOCK, 0, stream>>>(
        (const f4*)residual, (const f4*)sublayer, (f4*)out, W_raw,
        residual, sublayer, out, n4, n);
}